// Round 1
// baseline (233.996 us; speedup 1.0000x reference)
//
#include <hip/hip_runtime.h>
#include <stdint.h>
#include <math.h>

// ---------------------------------------------------------------------------
// IID segmentation loss on MI355X.
//
// Reformulation: p[dy,dx,n,o] = sum_{b,y,x} xo[b,n,y+dy-7,x+dx-7]*xt[b,o,y,x]
// is ONE GEMM:  C[(n,dx)][(o,dy)] = sum_k Atil[(n,dx)][k] * Btil[(o,dy)][k],
//   k=(b,y,x), Atil = xo x-shifted by dx-7 (zero pad), Btil = xt y-shifted by
//   7-dy (zero pad).  M=N=150 padded to 160 (dx=15/dy=15 phantom slots are
//   computed with finite garbage and ignored in the epilogue).
// K1: fused bf16 MFMA GEMM, split-K over (b, 7-row y strip) -> 512 partials.
// K2a/K2f: reduce 512 partials (fp32 then fp64), write C + per-block min.
// K3min: global min + zero d_out.  K4: per-shift fp64 loss, atomicAdd.
// ---------------------------------------------------------------------------

#define PADV 7
#define TS 15
#define KCLS 10
#define HH 224
#define WW 224
#define MD 160
#define NCELL (MD*MD)          // 25600
#define NBLK 512               // split-K partial count
#define TY 7                   // y rows per K1 block (32 strips * 7 = 224)
#define AROW 240               // staged A row length (x in [-7,233), padded)
#define BSTRIDE 232            // B window row stride (16B aligned, good banks)
#define LEPS 1e-16

typedef __attribute__((ext_vector_type(4))) float f32x4;
typedef __attribute__((ext_vector_type(8))) short bf16x8;

__device__ __forceinline__ unsigned short f2bf(float f) {
  // round-to-nearest-even f32 -> bf16 (unbiased; inputs are finite)
  union { float f; uint32_t u; } v; v.f = f;
  return (unsigned short)((v.u + 0x7FFFu + ((v.u >> 16) & 1u)) >> 16);
}

// ---------------------------------------------------------------- K1: GEMM
__global__ __launch_bounds__(256, 2)
void corr_gemm(const float* __restrict__ xo, const float* __restrict__ xt,
               float* __restrict__ partials) {
  // LDS: A = 10 classes x 240 (current y row, halo'd, bf16)         4800 B
  //      B = 10 classes x 16-slot circular row window x 232 elems  74240 B
  __shared__ __align__(16) unsigned short ldsA[KCLS * AROW];
  __shared__ __align__(16) unsigned short ldsB[KCLS * 16 * BSTRIDE];

  const int tid  = threadIdx.x;
  const int bid  = blockIdx.x;
  const int b    = bid >> 5;
  const int y0   = (bid & 31) * TY;

  const int lane = tid & 63;
  const int wv   = tid >> 6;
  const int wm   = wv & 1;        // M half (80 rows)
  const int wn   = wv >> 1;       // N half (80 cols)
  const int quad = lane >> 4;     // 0..3
  const int l15  = lane & 15;

  f32x4 acc[5][5];
#pragma unroll
  for (int i = 0; i < 5; ++i)
#pragma unroll
    for (int j = 0; j < 5; ++j) acc[i][j] = (f32x4){0.f, 0.f, 0.f, 0.f};

  const float* Ab = xo + (size_t)b * KCLS * HH * WW;
  const float* Bb = xt + (size_t)b * KCLS * HH * WW;

  // Preload B rows y0-7 .. y0+7 (15 rows), zero for OOB rows.
  for (int t = tid; t < 15 * KCLS * WW; t += 256) {
    int r15 = t / (KCLS * WW);
    int rem = t - r15 * (KCLS * WW);
    int o   = rem / WW;
    int x   = rem - o * WW;
    int row = y0 - PADV + r15;
    float v = (row >= 0 && row < HH) ? Bb[(o * HH + row) * WW + x] : 0.f;
    ldsB[(o * 16 + (row & 15)) * BSTRIDE + x] = f2bf(v);
  }

  for (int y = y0; y < y0 + TY; ++y) {
    __syncthreads();  // previous compute done before overwriting ldsA / B slot

    // Stage A row y: raw[n][i] = xo[b,n,y,i-7], zero-padded.
    for (int t = tid; t < KCLS * AROW; t += 256) {
      int n = t / AROW;
      int i = t - n * AROW;
      int x = i - PADV;
      float v = (x >= 0 && x < WW) ? Ab[(n * HH + y) * WW + x] : 0.f;
      ldsA[n * AROW + i] = f2bf(v);
    }
    // Stage B row y+8 into slot (y+8)&15 (fresh before this y's compute).
    {
      int row = y + 8;
      for (int t = tid; t < KCLS * WW; t += 256) {
        int o = t / WW;
        int x = t - o * WW;
        float v = (row < HH) ? Bb[(o * HH + row) * WW + x] : 0.f;
        ldsB[(o * 16 + (row & 15)) * BSTRIDE + x] = f2bf(v);
      }
    }
    __syncthreads();

    // 7 k-chunks of 32 along x
#pragma unroll 1
    for (int xc = 0; xc < 7; ++xc) {
      const int x0 = xc * 32;
      bf16x8 afrag[5], bfrag[5];

      // A-frags: lane holds Atil[m=16*tm+dx][k=x0+quad*8+j], dx=l15.
      // Element offset in raw row: e = x0 + quad*8 + j + dx. 8 contiguous
      // bf16 at element base e0 -> 5 aligned u32 + v_alignbit.
      const int e0 = x0 + quad * 8 + l15;
      const int q  = e0 >> 1;
      const int sh = (e0 & 1) << 4;
#pragma unroll
      for (int mi = 0; mi < 5; ++mi) {
        const int tm = wm * 5 + mi;  // class index n
        const uint32_t* pa = (const uint32_t*)ldsA + tm * (AROW / 2);
        uint32_t w0 = pa[q], w1 = pa[q + 1], w2 = pa[q + 2],
                 w3 = pa[q + 3], w4 = pa[q + 4];
        union { uint32_t u[4]; bf16x8 v; } cv;
        cv.u[0] = __builtin_amdgcn_alignbit(w1, w0, sh);
        cv.u[1] = __builtin_amdgcn_alignbit(w2, w1, sh);
        cv.u[2] = __builtin_amdgcn_alignbit(w3, w2, sh);
        cv.u[3] = __builtin_amdgcn_alignbit(w4, w3, sh);
        afrag[mi] = cv.v;
      }
      // B-frags: lane holds Btil[k][nn=16*to+dy], dy=l15 -> row y+7-dy,
      // 16B-aligned contiguous x run -> ds_read_b128.
      const int slot = (y + PADV - l15) & 15;
#pragma unroll
      for (int ni = 0; ni < 5; ++ni) {
        const int to = wn * 5 + ni;  // class index o
        bfrag[ni] = *(const bf16x8*)(ldsB + (to * 16 + slot) * BSTRIDE + x0 + quad * 8);
      }
#pragma unroll
      for (int mi = 0; mi < 5; ++mi)
#pragma unroll
        for (int ni = 0; ni < 5; ++ni)
          acc[mi][ni] = __builtin_amdgcn_mfma_f32_16x16x32_bf16(
              afrag[mi], bfrag[ni], acc[mi][ni], 0, 0, 0);
    }
  }

  // C/D layout (m89/m91): col = lane&15, row = quad*4 + reg.
  float* outp = partials + (size_t)bid * NCELL;
#pragma unroll
  for (int mi = 0; mi < 5; ++mi)
#pragma unroll
    for (int ni = 0; ni < 5; ++ni) {
      const int mrow = (wm * 5 + mi) * 16 + quad * 4;
      const int ncol = (wn * 5 + ni) * 16 + l15;
#pragma unroll
      for (int r = 0; r < 4; ++r)
        outp[(size_t)(mrow + r) * MD + ncol] = acc[mi][ni][r];
    }
}

// ------------------------------------------------- K2a: reduce 512 -> 8
__global__ __launch_bounds__(256)
void reduce_stage1(const float* __restrict__ partials, float* __restrict__ stage2) {
  const int c  = (blockIdx.x % 100) * 256 + threadIdx.x;
  const int pg = blockIdx.x / 100;  // 0..7
  const float* base = partials + (size_t)pg * 64 * NCELL + c;
  float s0 = 0.f, s1 = 0.f, s2 = 0.f, s3 = 0.f;
  for (int p = 0; p < 64; p += 4) {
    s0 += base[(size_t)(p + 0) * NCELL];
    s1 += base[(size_t)(p + 1) * NCELL];
    s2 += base[(size_t)(p + 2) * NCELL];
    s3 += base[(size_t)(p + 3) * NCELL];
  }
  stage2[(size_t)pg * NCELL + c] = (s0 + s1) + (s2 + s3);
}

// ---------------------------------------- K2f: 8 -> C (fp64) + block min
__global__ __launch_bounds__(256)
void reduce_final(const float* __restrict__ stage2, float* __restrict__ Cout,
                  float* __restrict__ mins) {
  const int c = blockIdx.x * 256 + threadIdx.x;
  double s = 0.0;
#pragma unroll
  for (int pg = 0; pg < 8; ++pg) s += (double)stage2[(size_t)pg * NCELL + c];
  const float sf = (float)s;
  Cout[c] = sf;
  const int m  = c / MD;
  const int nn = c - m * MD;
  const bool valid = ((m & 15) < TS) && ((nn & 15) < TS);  // drop phantoms
  __shared__ float red[256];
  red[threadIdx.x] = valid ? sf : 3.4e38f;
  __syncthreads();
  for (int st = 128; st > 0; st >>= 1) {
    if (threadIdx.x < st)
      red[threadIdx.x] = fminf(red[threadIdx.x], red[threadIdx.x + st]);
    __syncthreads();
  }
  if (threadIdx.x == 0) mins[blockIdx.x] = red[0];
}

// --------------------------------------------- K3: global min, zero out
__global__ void final_min(const float* __restrict__ mins, float* __restrict__ minout,
                          float* __restrict__ dout) {
  __shared__ float red[128];
  const int tid = threadIdx.x;
  red[tid] = (tid < 100) ? mins[tid] : 3.4e38f;
  __syncthreads();
  for (int st = 64; st > 0; st >>= 1) {
    if (tid < st) red[tid] = fminf(red[tid], red[tid + st]);
    __syncthreads();
  }
  if (tid == 0) { minout[0] = red[0]; dout[0] = 0.f; }
}

// -------------------------------------------- K4: per-shift loss (fp64)
__global__ __launch_bounds__(128)
void loss_kernel(const float* __restrict__ Cmat, const float* __restrict__ minp,
                 float* __restrict__ dout) {
  const int s   = blockIdx.x;   // 0..224
  const int dy  = s / TS;
  const int dx  = s - dy * TS;
  const int tid = threadIdx.x;
  __shared__ double q[100];
  __shared__ double sym[100];
  __shared__ double pi[10], pj[10];
  __shared__ double red[128];
  const double minv = (double)minp[0];
  if (tid < 100) {
    const int n = tid / 10, o = tid - (tid / 10) * 10;
    const double v = (double)Cmat[(size_t)(n * 16 + dx) * MD + (o * 16 + dy)];
    q[tid] = v - minv + LEPS;
  }
  __syncthreads();
  red[tid] = (tid < 100) ? q[tid] : 0.0;
  __syncthreads();
  for (int st = 64; st > 0; st >>= 1) {
    if (tid < st) red[tid] += red[tid + st];
    __syncthreads();
  }
  const double Z = red[0];
  __syncthreads();
  if (tid < 100) {
    const int n = tid / 10, o = tid - (tid / 10) * 10;
    sym[tid] = (q[n * 10 + o] + q[o * 10 + n]) * 0.5 / Z;
  }
  __syncthreads();
  if (tid < 10) {
    double a = 0.0, bsum = 0.0;
    for (int n2 = 0; n2 < 10; ++n2) {
      a    += sym[n2 * 10 + tid];   // p_i[o]: sum over n (axis 2)
      bsum += sym[tid * 10 + n2];   // p_j[n]: sum over o (axis 3)
    }
    pi[tid] = a;
    pj[tid] = bsum;
  }
  __syncthreads();
  double term = 0.0;
  if (tid < 100) {
    const int n = tid / 10, o = tid - (tid / 10) * 10;
    const double sp = sym[tid];
    term = -sp * (log(sp + LEPS) - log(pi[o] + LEPS) - log(pj[n] + LEPS));
  }
  red[tid] = term;
  __syncthreads();
  for (int st = 64; st > 0; st >>= 1) {
    if (tid < st) red[tid] += red[tid + st];
    __syncthreads();
  }
  if (tid == 0) atomicAdd(dout, (float)(red[0] / (double)(TS * TS)));
}

// ---------------------------------------------------------------------------
extern "C" void kernel_launch(void* const* d_in, const int* in_sizes, int n_in,
                              void* d_out, int out_size, void* d_ws, size_t ws_size,
                              hipStream_t stream) {
  const float* xo = (const float*)d_in[0];
  const float* xt = (const float*)d_in[1];
  float* ws       = (float*)d_ws;

  float* partials = ws;                                  // 512*25600
  float* stage2   = partials + (size_t)NBLK * NCELL;     // 8*25600
  float* Cmat     = stage2 + (size_t)8 * NCELL;          // 25600
  float* mins     = Cmat + NCELL;                        // 100 (pad 128)
  float* minf     = mins + 128;                          // 1
  float* out      = (float*)d_out;

  hipLaunchKernelGGL(corr_gemm,     dim3(NBLK), dim3(256), 0, stream, xo, xt, partials);
  hipLaunchKernelGGL(reduce_stage1, dim3(800),  dim3(256), 0, stream, partials, stage2);
  hipLaunchKernelGGL(reduce_final,  dim3(100),  dim3(256), 0, stream, stage2, Cmat, mins);
  hipLaunchKernelGGL(final_min,     dim3(1),    dim3(128), 0, stream, mins, minf, out);
  hipLaunchKernelGGL(loss_kernel,   dim3(225),  dim3(128), 0, stream, Cmat, minf, out);
}

// Round 2
// 155.163 us; speedup vs baseline: 1.5081x; 1.5081x over previous
//
#include <hip/hip_runtime.h>
#include <stdint.h>
#include <math.h>

// ---------------------------------------------------------------------------
// IID segmentation loss on MI355X.  Round 2 (clean).
// See analysis: K1 was latency-bound (all pipes <25%). B staging now via
// async global_load_lds from a pre-converted padded bf16 tensor, issued
// before compute; A row register-prefetched. Tail: final_min folded into
// loss_kernel, d_out zeroed in reduce_final.
// ---------------------------------------------------------------------------

#define PADV 7
#define TS 15
#define KCLS 10
#define HH 224
#define WW 224
#define MD 160
#define NCELL (MD*MD)
#define NBLK 512
#define TY 7
#define AROW 240
#define BSTRIDE 232
#define BPH 240
#define LEPS 1e-16

typedef __attribute__((ext_vector_type(4))) float f32x4;
typedef __attribute__((ext_vector_type(8))) short bf16x8;

__device__ __forceinline__ unsigned short f2bf(float f) {
  union { float f; uint32_t u; } v; v.f = f;
  return (unsigned short)((v.u + 0x7FFFu + ((v.u >> 16) & 1u)) >> 16);
}

__device__ __forceinline__ void glds16(const unsigned short* g, unsigned short* l) {
  __builtin_amdgcn_global_load_lds(
      (const __attribute__((address_space(1))) unsigned int*)g,
      (__attribute__((address_space(3))) unsigned int*)l, 16, 0, 0);
}

// Bpad[cls][yy][x]: cls=b*10+o, yy in [0,240) <-> row=yy-7, x in [0,232).
__global__ __launch_bounds__(256)
void prep_b(const float* __restrict__ xt, unsigned short* __restrict__ bp) {
  const int idx   = blockIdx.x * 256 + threadIdx.x;
  const int rowid = idx / 29;
  const int chunk = idx - rowid * 29;
  const int x0    = chunk * 8;
  const int yy    = rowid % BPH;
  const int cls   = rowid / BPH;
  const int row   = yy - PADV;
  union { unsigned short h[8]; uint4 v; } out;
  if (row >= 0 && row < HH && x0 < WW) {
    const float* src = xt + ((size_t)cls * HH + row) * WW + x0;
#pragma unroll
    for (int j = 0; j < 8; ++j) out.h[j] = f2bf(src[j]);
  } else {
    out.v = make_uint4(0u, 0u, 0u, 0u);
  }
  *(uint4*)(bp + (size_t)rowid * BSTRIDE + x0) = out.v;
}

__global__ __launch_bounds__(256, 2)
void corr_gemm(const float* __restrict__ xo, const unsigned short* __restrict__ bpad,
               float* __restrict__ partials) {
  __shared__ __align__(16) unsigned short ldsA[KCLS * AROW];
  __shared__ __align__(16) unsigned short ldsB[KCLS * 16 * BSTRIDE];

  const int tid  = threadIdx.x;
  const int bid  = blockIdx.x;
  const int b    = bid >> 5;
  const int y0   = (bid & 31) * TY;

  const int lane = tid & 63;
  const int wv   = tid >> 6;
  const int wm   = wv & 1;
  const int wn   = wv >> 1;
  const int quad = lane >> 4;
  const int l15  = lane & 15;

  f32x4 acc[5][5];
#pragma unroll
  for (int i = 0; i < 5; ++i)
#pragma unroll
    for (int j = 0; j < 5; ++j) acc[i][j] = (f32x4){0.f, 0.f, 0.f, 0.f};

  const float* Ab = xo + (size_t)b * KCLS * HH * WW;
  const unsigned short* Bb = bpad + (size_t)b * KCLS * BPH * BSTRIDE;

  // prologue: async preload B rows y0-7..y0+7 (150 class-rows)
  for (int pr = wv; pr < 15 * KCLS; pr += 4) {
    const int r15  = pr / KCLS;
    const int o    = pr - r15 * KCLS;
    const int yy   = y0 + r15;                 // row = y0-7+r15
    const int slot = (y0 - PADV + r15) & 15;
    if (lane < 29)
      glds16(Bb + ((size_t)o * BPH + yy) * BSTRIDE + lane * 8,
             ldsB + (o * 16 + slot) * BSTRIDE);
  }

  // prologue: A row y0 -> LDS
#pragma unroll
  for (int r = 0; r < 10; ++r) {
    const int t = tid + r * 256;
    if (t < KCLS * AROW) {
      const int n = t / AROW;
      const int i = t - n * AROW;
      const int x = i - PADV;
      float v = 0.f;
      if (x >= 0 && x < WW) v = Ab[((size_t)n * HH + y0) * WW + x];
      ldsA[t] = f2bf(v);
    }
  }
  __syncthreads();  // drains B DMA + publishes A row y0

  float va[10];
  for (int y = y0; y < y0 + TY; ++y) {
    const bool more = (y + 1 < y0 + TY);

    if (more) {
      // async DMA: B row y+8 into dead slot
      const int yy   = y + 8 + PADV;
      const int slot = (y + 8) & 15;
      for (int ro = wv; ro < KCLS; ro += 4) {
        if (lane < 29)
          glds16(Bb + ((size_t)ro * BPH + yy) * BSTRIDE + lane * 8,
                 ldsB + (ro * 16 + slot) * BSTRIDE);
      }
      // register prefetch: A row y+1
      const int yl = y + 1;
#pragma unroll
      for (int r = 0; r < 10; ++r) {
        const int t = tid + r * 256;
        float v = 0.f;
        if (t < KCLS * AROW) {
          const int n = t / AROW;
          const int i = t - n * AROW;
          const int x = i - PADV;
          if (x >= 0 && x < WW) v = Ab[((size_t)n * HH + yl) * WW + x];
        }
        va[r] = v;
      }
    }

#pragma unroll 1
    for (int xc = 0; xc < 7; ++xc) {
      const int x0 = xc * 32;
      bf16x8 afrag[5], bfrag[5];
      const int e0 = x0 + quad * 8 + l15;
      const int q  = e0 >> 1;
      const int sh = (e0 & 1) << 4;
#pragma unroll
      for (int mi = 0; mi < 5; ++mi) {
        const int tm = wm * 5 + mi;
        const uint32_t* pa = (const uint32_t*)ldsA + tm * (AROW / 2);
        uint32_t w0 = pa[q], w1 = pa[q + 1], w2 = pa[q + 2],
                 w3 = pa[q + 3], w4 = pa[q + 4];
        union { uint32_t u[4]; bf16x8 v; } cv;
        cv.u[0] = __builtin_amdgcn_alignbit(w1, w0, sh);
        cv.u[1] = __builtin_amdgcn_alignbit(w2, w1, sh);
        cv.u[2] = __builtin_amdgcn_alignbit(w3, w2, sh);
        cv.u[3] = __builtin_amdgcn_alignbit(w4, w3, sh);
        afrag[mi] = cv.v;
      }
      const int slot = (y + PADV - l15) & 15;
#pragma unroll
      for (int ni = 0; ni < 5; ++ni) {
        const int to = wn * 5 + ni;
        bfrag[ni] = *(const bf16x8*)(ldsB + (to * 16 + slot) * BSTRIDE + x0 + quad * 8);
      }
#pragma unroll
      for (int mi = 0; mi < 5; ++mi)
#pragma unroll
        for (int ni = 0; ni < 5; ++ni)
          acc[mi][ni] = __builtin_amdgcn_mfma_f32_16x16x32_bf16(
              afrag[mi], bfrag[ni], acc[mi][ni], 0, 0, 0);
    }

    if (more) {
      __syncthreads();
#pragma unroll
      for (int r = 0; r < 10; ++r) {
        const int t = tid + r * 256;
        if (t < KCLS * AROW) ldsA[t] = f2bf(va[r]);
      }
      __syncthreads();
    }
  }

  float* outp = partials + (size_t)bid * NCELL;
#pragma unroll
  for (int mi = 0; mi < 5; ++mi)
#pragma unroll
    for (int ni = 0; ni < 5; ++ni) {
      const int mrow = (wm * 5 + mi) * 16 + quad * 4;
      const int ncol = (wn * 5 + ni) * 16 + l15;
#pragma unroll
      for (int r = 0; r < 4; ++r)
        outp[(size_t)(mrow + r) * MD + ncol] = acc[mi][ni][r];
    }
}

__global__ __launch_bounds__(256)
void reduce_stage1(const float* __restrict__ partials, float* __restrict__ stage2) {
  const int c  = (blockIdx.x % 100) * 256 + threadIdx.x;
  const int pg = blockIdx.x / 100;
  const float* base = partials + (size_t)pg * 64 * NCELL + c;
  float s0 = 0.f, s1 = 0.f, s2 = 0.f, s3 = 0.f;
  for (int p = 0; p < 64; p += 4) {
    s0 += base[(size_t)(p + 0) * NCELL];
    s1 += base[(size_t)(p + 1) * NCELL];
    s2 += base[(size_t)(p + 2) * NCELL];
    s3 += base[(size_t)(p + 3) * NCELL];
  }
  stage2[(size_t)pg * NCELL + c] = (s0 + s1) + (s2 + s3);
}

__global__ __launch_bounds__(256)
void reduce_final(const float* __restrict__ stage2, float* __restrict__ Cout,
                  float* __restrict__ mins, float* __restrict__ dout) {
  const int c = blockIdx.x * 256 + threadIdx.x;
  if (blockIdx.x == 0 && threadIdx.x == 0) dout[0] = 0.f;
  double s = 0.0;
#pragma unroll
  for (int pg = 0; pg < 8; ++pg) s += (double)stage2[(size_t)pg * NCELL + c];
  const float sf = (float)s;
  Cout[c] = sf;
  const int m  = c / MD;
  const int nn = c - m * MD;
  const bool valid = ((m & 15) < TS) && ((nn & 15) < TS);
  __shared__ float red[256];
  red[threadIdx.x] = valid ? sf : 3.4e38f;
  __syncthreads();
  for (int st = 128; st > 0; st >>= 1) {
    if (threadIdx.x < st)
      red[threadIdx.x] = fminf(red[threadIdx.x], red[threadIdx.x + st]);
    __syncthreads();
  }
  if (threadIdx.x == 0) mins[blockIdx.x] = red[0];
}

__global__ __launch_bounds__(128)
void loss_kernel(const float* __restrict__ Cmat, const float* __restrict__ mins,
                 float* __restrict__ dout) {
  const int s   = blockIdx.x;
  const int dy  = s / TS;
  const int dx  = s - dy * TS;
  const int tid = threadIdx.x;
  __shared__ float fm[128];
  __shared__ double q[100];
  __shared__ double sym[100];
  __shared__ double pi[10], pj[10];
  __shared__ double red[128];

  fm[tid] = (tid < 100) ? mins[tid] : 3.4e38f;
  __syncthreads();
  for (int st = 64; st > 0; st >>= 1) {
    if (tid < st) fm[tid] = fminf(fm[tid], fm[tid + st]);
    __syncthreads();
  }
  const double minv = (double)fm[0];
  __syncthreads();

  if (tid < 100) {
    const int n = tid / 10, o = tid - (tid / 10) * 10;
    const double v = (double)Cmat[(size_t)(n * 16 + dx) * MD + (o * 16 + dy)];
    q[tid] = v - minv + LEPS;
  }
  __syncthreads();
  red[tid] = (tid < 100) ? q[tid] : 0.0;
  __syncthreads();
  for (int st = 64; st > 0; st >>= 1) {
    if (tid < st) red[tid] += red[tid + st];
    __syncthreads();
  }
  const double Z = red[0];
  __syncthreads();
  if (tid < 100) {
    const int n = tid / 10, o = tid - (tid / 10) * 10;
    sym[tid] = (q[n * 10 + o] + q[o * 10 + n]) * 0.5 / Z;
  }
  __syncthreads();
  if (tid < 10) {
    double a = 0.0, bsum = 0.0;
    for (int n2 = 0; n2 < 10; ++n2) {
      a    += sym[n2 * 10 + tid];
      bsum += sym[tid * 10 + n2];
    }
    pi[tid] = a;
    pj[tid] = bsum;
  }
  __syncthreads();
  double term = 0.0;
  if (tid < 100) {
    const int n = tid / 10, o = tid - (tid / 10) * 10;
    const double sp = sym[tid];
    term = -sp * (log(sp + LEPS) - log(pi[o] + LEPS) - log(pj[n] + LEPS));
  }
  red[tid] = term;
  __syncthreads();
  for (int st = 64; st > 0; st >>= 1) {
    if (tid < st) red[tid] += red[tid + st];
    __syncthreads();
  }
  if (tid == 0) atomicAdd(dout, (float)(red[0] / (double)(TS * TS)));
}

extern "C" void kernel_launch(void* const* d_in, const int* in_sizes, int n_in,
                              void* d_out, int out_size, void* d_ws, size_t ws_size,
                              hipStream_t stream) {
  const float* xo = (const float*)d_in[0];
  const float* xt = (const float*)d_in[1];
  float* ws       = (float*)d_ws;

  float* partials = ws;
  float* stage2   = partials + (size_t)NBLK * NCELL;
  float* Cmat     = stage2 + (size_t)8 * NCELL;
  float* mins     = Cmat + NCELL;
  unsigned short* bpad = (unsigned short*)(mins + 128);
  float* out      = (float*)d_out;

  hipLaunchKernelGGL(prep_b,        dim3(4350), dim3(256), 0, stream, xt, bpad);
  hipLaunchKernelGGL(corr_gemm,     dim3(NBLK), dim3(256), 0, stream, xo, bpad, partials);
  hipLaunchKernelGGL(reduce_stage1, dim3(800),  dim3(256), 0, stream, partials, stage2);
  hipLaunchKernelGGL(reduce_final,  dim3(100),  dim3(256), 0, stream, stage2, Cmat, mins, out);
  hipLaunchKernelGGL(loss_kernel,   dim3(225),  dim3(128), 0, stream, Cmat, mins, out);
}